// Round 1
// baseline (1850.794 us; speedup 1.0000x reference)
//
#include <hip/hip_runtime.h>
#include <math.h>

// Problem constants (DualAttention): B=64, S=2048, H=512, F=128, all fp32.
#define NB 64
#define NS 2048
#define NH 512
#define NF 128

// ---------------------------------------------------------------------------
// Kernel A: proj_in_a = tanh(input @ W_a + b_a), proj_in_b = tanh(input @ W_b + b_b)
// [B,H] each. Tiny (34 MFLOP). One block per batch row.
// ---------------------------------------------------------------------------
__global__ __launch_bounds__(256) void proj_in_kernel(
    const float* __restrict__ input,
    const float* __restrict__ W_a, const float* __restrict__ b_a,
    const float* __restrict__ W_b, const float* __restrict__ b_b,
    float* __restrict__ pa, float* __restrict__ pb) {
  __shared__ float sin_[NH];
  const int b = blockIdx.x, t = threadIdx.x;
  sin_[t]       = input[b * NH + t];
  sin_[t + 256] = input[b * NH + t + 256];
  __syncthreads();
#pragma unroll
  for (int rep = 0; rep < 2; ++rep) {
    const int h = t + rep * 256;
    float aa = 0.f, ab = 0.f;
    for (int k = 0; k < NH; ++k) {
      const float x = sin_[k];
      aa = fmaf(x, W_a[k * NH + h], aa);
      ab = fmaf(x, W_b[k * NH + h], ab);
    }
    pa[b * NH + h] = tanhf(aa + b_a[h]);
    pb[b * NH + h] = tanhf(ab + b_b[h]);
  }
}

// ---------------------------------------------------------------------------
// Kernel B: fused score GEMM.
//   score[r] = sum_h tanh( (A[r,:] @ W[:,h]) + bias[h] ) * pin[b,h]
// A: [B*S, K] row-major, W: [K, NH] row-major. Never materializes the
// [B,S,H] projected tensor (saves 256 MB of HBM round-trip each way).
// Block: 256 threads, 32 rows. Thread owns columns {t, t+256}.
// A-tile staged in LDS (broadcast reads); W streamed from L2 (1 MB, resident).
// ---------------------------------------------------------------------------
template <int K>
__global__ __launch_bounds__(256) void score_kernel(
    const float* __restrict__ A, const float* __restrict__ W,
    const float* __restrict__ bias, const float* __restrict__ pin,
    float* __restrict__ score) {
  constexpr int MT = 32;
  __shared__ float lA[MT][32];      // 4 KB A tile
  __shared__ float red[MT * 256];   // 32 KB epilogue reduction buffer
  const int t = threadIdx.x;
  const int row0 = blockIdx.x * MT;     // 32 rows, always within one batch b
  const int b = row0 >> 11;             // row0 / S
  const int c0 = t, c1 = t + 256;

  float acc0[MT], acc1[MT];
#pragma unroll
  for (int m = 0; m < MT; ++m) { acc0[m] = 0.f; acc1[m] = 0.f; }

  for (int k0 = 0; k0 < K; k0 += 32) {
    __syncthreads();
#pragma unroll
    for (int i = 0; i < 4; ++i) {       // stage 32x32 A tile
      const int idx = t + i * 256;
      const int r = idx >> 5, kk = idx & 31;
      lA[r][kk] = A[(size_t)(row0 + r) * K + k0 + kk];
    }
    __syncthreads();
    for (int kk = 0; kk < 32; kk += 4) {
      const float* Wp = W + (size_t)(k0 + kk) * NH;
      const float w00 = Wp[c0],          w01 = Wp[NH + c0],
                  w02 = Wp[2 * NH + c0], w03 = Wp[3 * NH + c0];
      const float w10 = Wp[c1],          w11 = Wp[NH + c1],
                  w12 = Wp[2 * NH + c1], w13 = Wp[3 * NH + c1];
#pragma unroll
      for (int m = 0; m < MT; ++m) {
        const float4 av = *(const float4*)&lA[m][kk];  // wave-uniform broadcast
        acc0[m] = fmaf(av.w, w03, fmaf(av.z, w02, fmaf(av.y, w01, fmaf(av.x, w00, acc0[m]))));
        acc1[m] = fmaf(av.w, w13, fmaf(av.z, w12, fmaf(av.y, w11, fmaf(av.x, w10, acc1[m]))));
      }
    }
  }

  // Epilogue: tanh + weighted reduce over the 512 columns.
  const float bias0 = bias[c0], bias1 = bias[c1];
  const float p0 = pin[b * NH + c0], p1 = pin[b * NH + c1];
  __syncthreads();
#pragma unroll
  for (int m = 0; m < MT; ++m)
    red[m * 256 + t] = tanhf(acc0[m] + bias0) * p0 + tanhf(acc1[m] + bias1) * p1;
  __syncthreads();
  const int wave = t >> 6, lane = t & 63;
  for (int m = wave; m < MT; m += 4) {
    float v = red[m * 256 + lane]       + red[m * 256 + lane + 64] +
              red[m * 256 + lane + 128] + red[m * 256 + lane + 192];
#pragma unroll
    for (int off = 32; off; off >>= 1) v += __shfl_down(v, off);
    if (lane == 0) score[row0 + m] = v;
  }
}

// ---------------------------------------------------------------------------
// Kernel C: gamma = softmax_S(score_a + score_b).
// (softmax(a)*softmax(b) L1-renormalized == softmax(a+b), exactly.)
// One block per batch; 8 elements per thread held in registers.
// ---------------------------------------------------------------------------
__global__ __launch_bounds__(256) void gamma_kernel(
    const float* __restrict__ sa, const float* __restrict__ sb,
    float* __restrict__ gamma) {
  const int b = blockIdx.x, t = threadIdx.x;
  __shared__ float swp[4];
  float v[8];
  float mx = -1e30f;
#pragma unroll
  for (int i = 0; i < 8; ++i) {
    const int s = t + i * 256;
    v[i] = sa[b * NS + s] + sb[b * NS + s];
    mx = fmaxf(mx, v[i]);
  }
  const int wave = t >> 6, lane = t & 63;
#pragma unroll
  for (int off = 32; off; off >>= 1) mx = fmaxf(mx, __shfl_down(mx, off));
  if (lane == 0) swp[wave] = mx;
  __syncthreads();
  mx = fmaxf(fmaxf(swp[0], swp[1]), fmaxf(swp[2], swp[3]));
  __syncthreads();
  float sum = 0.f;
#pragma unroll
  for (int i = 0; i < 8; ++i) {
    v[i] = expf(v[i] - mx);
    sum += v[i];
  }
#pragma unroll
  for (int off = 32; off; off >>= 1) sum += __shfl_down(sum, off);
  if (lane == 0) swp[wave] = sum;
  __syncthreads();
  const float inv = 1.f / (swp[0] + swp[1] + swp[2] + swp[3]);
#pragma unroll
  for (int i = 0; i < 8; ++i) gamma[b * NS + t + i * 256] = v[i] * inv;
}

// ---------------------------------------------------------------------------
// Kernel D: weighted context partial sums. wcp[b,chunk,h] = sum over 256 s of
// gamma[b,s]*context[b,s,h]. Memory-bound: re-reads context (256 MB).
// Grid (B, 8): 512 blocks, float2 per thread.
// ---------------------------------------------------------------------------
__global__ __launch_bounds__(256) void wctx_kernel(
    const float* __restrict__ ctx, const float* __restrict__ gamma,
    float* __restrict__ wcp) {
  const int b = blockIdx.x, ch = blockIdx.y, t = threadIdx.x;
  __shared__ float g[256];
  const int s0 = ch * 256;
  g[t] = gamma[b * NS + s0 + t];
  __syncthreads();
  float2 acc = make_float2(0.f, 0.f);
  const float* base = ctx + (size_t)(b * NS + s0) * NH + 2 * t;
#pragma unroll 8
  for (int s = 0; s < 256; ++s) {
    const float gs = g[s];
    const float2 c = *(const float2*)(base + (size_t)s * NH);
    acc.x = fmaf(gs, c.x, acc.x);
    acc.y = fmaf(gs, c.y, acc.y);
  }
  *(float2*)&wcp[(size_t)(b * 8 + ch) * NH + 2 * t] = acc;
}

// ---------------------------------------------------------------------------
// Kernel E: reduce partials -> wc[b,:], h_tilde = tanh([wc, input] @ W_out).
// W_out: [2H, H] row-major. One block per batch.
// ---------------------------------------------------------------------------
__global__ __launch_bounds__(256) void out_kernel(
    const float* __restrict__ wcp, const float* __restrict__ input,
    const float* __restrict__ W_out, float* __restrict__ out) {
  __shared__ float cat[2 * NH];
  const int b = blockIdx.x, t = threadIdx.x;
#pragma unroll
  for (int rep = 0; rep < 2; ++rep) {
    const int h = t + rep * 256;
    float s = 0.f;
#pragma unroll
    for (int c = 0; c < 8; ++c) s += wcp[(size_t)(b * 8 + c) * NH + h];
    cat[h] = s;                       // weighted_context first
    cat[NH + h] = input[b * NH + h];  // then input
  }
  __syncthreads();
#pragma unroll
  for (int rep = 0; rep < 2; ++rep) {
    const int o = t + rep * 256;
    float acc = 0.f;
    for (int k = 0; k < 2 * NH; ++k) acc = fmaf(cat[k], W_out[(size_t)k * NH + o], acc);
    out[b * NH + o] = tanhf(acc);
  }
}

// ---------------------------------------------------------------------------
extern "C" void kernel_launch(void* const* d_in, const int* in_sizes, int n_in,
                              void* d_out, int out_size, void* d_ws, size_t ws_size,
                              hipStream_t stream) {
  const float* input   = (const float*)d_in[0];
  const float* context = (const float*)d_in[1];
  const float* input_z = (const float*)d_in[2];
  const float* W_enc   = (const float*)d_in[3];
  const float* b_enc   = (const float*)d_in[4];
  const float* W_a     = (const float*)d_in[5];
  const float* b_a     = (const float*)d_in[6];
  const float* W_b     = (const float*)d_in[7];
  const float* b_b     = (const float*)d_in[8];
  const float* W_z     = (const float*)d_in[9];
  const float* b_z     = (const float*)d_in[10];
  const float* W_out   = (const float*)d_in[11];

  float* out = (float*)d_out;       // [0,32768): h_tilde, [32768,163840): gamma
  float* ws  = (float*)d_ws;
  float* pa  = ws;                  // B*H     = 32768
  float* pb  = ws + 32768;          // B*H     = 32768
  float* sa  = ws + 65536;          // B*S     = 131072
  float* sb  = ws + 196608;         // B*S     = 131072
  float* wcp = ws + 327680;         // B*8*H   = 262144
  float* gamma = out + NB * NH;

  hipLaunchKernelGGL(proj_in_kernel, dim3(NB), dim3(256), 0, stream,
                     input, W_a, b_a, W_b, b_b, pa, pb);
  hipLaunchKernelGGL(score_kernel<NH>, dim3(NB * NS / 32), dim3(256), 0, stream,
                     context, W_enc, b_enc, pa, sa);
  hipLaunchKernelGGL(score_kernel<NF>, dim3(NB * NS / 32), dim3(256), 0, stream,
                     input_z, W_z, b_z, pb, sb);
  hipLaunchKernelGGL(gamma_kernel, dim3(NB), dim3(256), 0, stream, sa, sb, gamma);
  hipLaunchKernelGGL(wctx_kernel, dim3(NB, 8), dim3(256), 0, stream,
                     context, gamma, wcp);
  hipLaunchKernelGGL(out_kernel, dim3(NB), dim3(256), 0, stream,
                     wcp, input, W_out, out);
}

// Round 2
// 885.981 us; speedup vs baseline: 2.0890x; 2.0890x over previous
//
#include <hip/hip_runtime.h>
#include <math.h>

// DualAttention: B=64, S=2048, H=512, F=128, fp32 in/out.
#define NB 64
#define NS 2048
#define NH 512
#define NF 128

typedef __attribute__((ext_vector_type(8))) short bf16x8;   // 8 bf16 = 4 VGPRs
typedef __attribute__((ext_vector_type(4))) float f32x4;    // MFMA C/D

__device__ inline unsigned short f2bf(float x) {            // fp32->bf16 RNE
  union { float f; unsigned u; } v; v.f = x;
  unsigned r = v.u + 0x7fff + ((v.u >> 16) & 1);
  return (unsigned short)(r >> 16);
}
__device__ inline float bf2f(unsigned short b) {
  union { float f; unsigned u; } v; v.u = ((unsigned)b) << 16; return v.f;
}
__device__ inline float fast_tanh(float x) {
  // tanh(x) = 1 - 2/(e^{2x}+1); |x| <~ 8 here, no overflow concern.
  float e = __expf(2.f * x);
  return 1.f - 2.f / (e + 1.f);
}

// ---------------------------------------------------------------------------
// Pack W [K,512] row-major fp32 -> MFMA B-frag layout, split hi/lo bf16.
// Dest layout [K/32][32 ntiles][64 lanes][8 j]: dest index == tid.
// Source: k = kt*32 + (lane>>4)*8 + j ; n = nt*16 + (lane&15).
// ---------------------------------------------------------------------------
__global__ __launch_bounds__(256) void pack_w_kernel(
    const float* __restrict__ W, unsigned short* __restrict__ hi,
    unsigned short* __restrict__ lo) {
  const int tid = blockIdx.x * 256 + threadIdx.x;
  const int j = tid & 7, l = (tid >> 3) & 63, nt = (tid >> 9) & 31, kt = tid >> 14;
  const int k = kt * 32 + (l >> 4) * 8 + j;
  const int n = nt * 16 + (l & 15);
  const float x = W[k * NH + n];
  const unsigned short h = f2bf(x);
  hi[tid] = h;
  lo[tid] = f2bf(x - bf2f(h));
}

// ---------------------------------------------------------------------------
// Fused score GEMM via split-bf16 MFMA (3 products ~ fp32 precision):
//   score[r] = sum_n tanh((A[r,:] @ W[:,n]) + bias[n]) * pin[b,n]
// Block: 256 thr = 4 waves, M=32 rows, N=512 (wave w owns cols [w*128,w*128+128)).
// A staged in LDS as split bf16 (row stride 40 -> 16B-aligned b128, 2-way banks).
// W frags from L2 (1 MB resident), lane-contiguous dwordx4.
// ---------------------------------------------------------------------------
template <int K>
__global__ __launch_bounds__(256) void score_mfma(
    const float* __restrict__ A,
    const unsigned short* __restrict__ Whi, const unsigned short* __restrict__ Wlo,
    const float* __restrict__ bias, const float* __restrict__ pin,
    float* __restrict__ score) {
  constexpr int KT = K / 32;
  __shared__ __align__(16) unsigned short lAhi[32 * 40];
  __shared__ __align__(16) unsigned short lAlo[32 * 40];
  __shared__ float red[4 * 32];
  const int t = threadIdx.x;
  const int wave = t >> 6, lane = t & 63;
  const int row0 = blockIdx.x * 32;
  const int b = row0 >> 11;  // row0 / S

  f32x4 acc[2][8];
#pragma unroll
  for (int mt = 0; mt < 2; ++mt)
#pragma unroll
    for (int nt = 0; nt < 8; ++nt) acc[mt][nt] = (f32x4)0.f;

  // staging assignment: thread t loads 4 fp32 of row lr at col lc
  const int lr = t >> 3, lc = (t & 7) * 4;
  const float* Ab = A + (size_t)(row0 + lr) * K + lc;
  // A-frag LDS read address (bytes/2): row (mt*16 + lane&15), koff (lane>>4)*8
  const int fr = (lane & 15), fq = (lane >> 4);

  for (int kt = 0; kt < KT; ++kt) {
    const float4 av = *(const float4*)(Ab + kt * 32);   // prefetch before barrier
    __syncthreads();                                    // prev-iter LDS reads done
    unsigned short h0 = f2bf(av.x), h1 = f2bf(av.y), h2 = f2bf(av.z), h3 = f2bf(av.w);
    *(ushort4*)&lAhi[lr * 40 + lc] = make_ushort4(h0, h1, h2, h3);
    *(ushort4*)&lAlo[lr * 40 + lc] = make_ushort4(
        f2bf(av.x - bf2f(h0)), f2bf(av.y - bf2f(h1)),
        f2bf(av.z - bf2f(h2)), f2bf(av.w - bf2f(h3)));
    __syncthreads();

    bf16x8 ah[2], al[2];
#pragma unroll
    for (int mt = 0; mt < 2; ++mt) {
      const int ra = (mt * 16 + fr) * 40 + fq * 8;
      ah[mt] = *(const bf16x8*)&lAhi[ra];
      al[mt] = *(const bf16x8*)&lAlo[ra];
    }
#pragma unroll
    for (int nt = 0; nt < 8; ++nt) {
      const int ntg = wave * 8 + nt;
      const size_t widx = (size_t)(kt * 32 + ntg) * 64 + lane;  // 16B units
      const bf16x8 wh = ((const bf16x8*)Whi)[widx];
      const bf16x8 wl = ((const bf16x8*)Wlo)[widx];
#pragma unroll
      for (int mt = 0; mt < 2; ++mt) {
        acc[mt][nt] = __builtin_amdgcn_mfma_f32_16x16x32_bf16(ah[mt], wh, acc[mt][nt], 0, 0, 0);
        acc[mt][nt] = __builtin_amdgcn_mfma_f32_16x16x32_bf16(ah[mt], wl, acc[mt][nt], 0, 0, 0);
        acc[mt][nt] = __builtin_amdgcn_mfma_f32_16x16x32_bf16(al[mt], wh, acc[mt][nt], 0, 0, 0);
      }
    }
  }

  // Epilogue: tanh + weighted column-reduce.
  // C layout: col = lane&15 (+nt*16+wave*128), row = (lane>>4)*4 + reg (+mt*16).
  float ps[2][4];
#pragma unroll
  for (int mt = 0; mt < 2; ++mt)
#pragma unroll
    for (int r = 0; r < 4; ++r) ps[mt][r] = 0.f;
#pragma unroll
  for (int nt = 0; nt < 8; ++nt) {
    const int col = wave * 128 + nt * 16 + fr;
    const float bi = bias[col], pi = pin[b * NH + col];
#pragma unroll
    for (int mt = 0; mt < 2; ++mt)
#pragma unroll
      for (int r = 0; r < 4; ++r)
        ps[mt][r] += fast_tanh(acc[mt][nt][r] + bi) * pi;
  }
#pragma unroll
  for (int m = 8; m; m >>= 1)
#pragma unroll
    for (int mt = 0; mt < 2; ++mt)
#pragma unroll
      for (int r = 0; r < 4; ++r) ps[mt][r] += __shfl_xor(ps[mt][r], m);
  if (fr == 0) {
#pragma unroll
    for (int mt = 0; mt < 2; ++mt)
#pragma unroll
      for (int r = 0; r < 4; ++r) red[wave * 32 + mt * 16 + fq * 4 + r] = ps[mt][r];
  }
  __syncthreads();
  if (t < 32) score[row0 + t] = red[t] + red[32 + t] + red[64 + t] + red[96 + t];
}

// ---------------------------------------------------------------------------
// proj_in: tanh(input @ W_{a,b} + b_{a,b}); grid (B,4): y<2 -> a, y&1 -> half.
// ---------------------------------------------------------------------------
__global__ __launch_bounds__(256) void proj_in_kernel(
    const float* __restrict__ input,
    const float* __restrict__ W_a, const float* __restrict__ b_a,
    const float* __restrict__ W_b, const float* __restrict__ b_b,
    float* __restrict__ pa, float* __restrict__ pb) {
  __shared__ float sin_[NH];
  const int b = blockIdx.x, part = blockIdx.y, t = threadIdx.x;
  const float* W  = (part < 2) ? W_a : W_b;
  const float* bi = (part < 2) ? b_a : b_b;
  float* out      = (part < 2) ? pa : pb;
  const int h = t + (part & 1) * 256;
  sin_[t] = input[b * NH + t];
  sin_[t + 256] = input[b * NH + t + 256];
  __syncthreads();
  float acc = 0.f;
  for (int k = 0; k < NH; ++k) acc = fmaf(sin_[k], W[k * NH + h], acc);
  out[b * NH + h] = tanhf(acc + bi[h]);
}

// ---------------------------------------------------------------------------
// gamma = softmax_S(score_a + score_b)  (== renormalized softmax product)
// ---------------------------------------------------------------------------
__global__ __launch_bounds__(256) void gamma_kernel(
    const float* __restrict__ sa, const float* __restrict__ sb,
    float* __restrict__ gamma) {
  const int b = blockIdx.x, t = threadIdx.x;
  __shared__ float swp[4];
  float v[8];
  float mx = -1e30f;
#pragma unroll
  for (int i = 0; i < 8; ++i) {
    const int s = t + i * 256;
    v[i] = sa[b * NS + s] + sb[b * NS + s];
    mx = fmaxf(mx, v[i]);
  }
  const int wave = t >> 6, lane = t & 63;
#pragma unroll
  for (int off = 32; off; off >>= 1) mx = fmaxf(mx, __shfl_down(mx, off));
  if (lane == 0) swp[wave] = mx;
  __syncthreads();
  mx = fmaxf(fmaxf(swp[0], swp[1]), fmaxf(swp[2], swp[3]));
  __syncthreads();
  float sum = 0.f;
#pragma unroll
  for (int i = 0; i < 8; ++i) {
    v[i] = __expf(v[i] - mx);
    sum += v[i];
  }
#pragma unroll
  for (int off = 32; off; off >>= 1) sum += __shfl_down(sum, off);
  if (lane == 0) swp[wave] = sum;
  __syncthreads();
  const float inv = 1.f / (swp[0] + swp[1] + swp[2] + swp[3]);
#pragma unroll
  for (int i = 0; i < 8; ++i) gamma[b * NS + t + i * 256] = v[i] * inv;
}

// ---------------------------------------------------------------------------
// wctx partials: grid (B,8); block covers 256 s; halves of 128 s per thread-half.
// float4 columns. wcp has 16 chunks per batch.
// ---------------------------------------------------------------------------
__global__ __launch_bounds__(256) void wctx_kernel(
    const float* __restrict__ ctx, const float* __restrict__ gamma,
    float* __restrict__ wcp) {
  const int b = blockIdx.x, ch = blockIdx.y, t = threadIdx.x;
  __shared__ float g[256];
  const int s0 = ch * 256;
  g[t] = gamma[b * NS + s0 + t];
  __syncthreads();
  const int sh = t >> 7, h4 = (t & 127) * 4;
  float4 acc = make_float4(0.f, 0.f, 0.f, 0.f);
  const float* base = ctx + (size_t)(b * NS + s0 + sh * 128) * NH + h4;
#pragma unroll 4
  for (int s = 0; s < 128; ++s) {
    const float gs = g[sh * 128 + s];
    const float4 c = *(const float4*)(base + (size_t)s * NH);
    acc.x = fmaf(gs, c.x, acc.x);
    acc.y = fmaf(gs, c.y, acc.y);
    acc.z = fmaf(gs, c.z, acc.z);
    acc.w = fmaf(gs, c.w, acc.w);
  }
  *(float4*)&wcp[(size_t)(b * 16 + ch * 2 + sh) * NH + h4] = acc;
}

// ---------------------------------------------------------------------------
// out: reduce 16 wcp chunks -> wc; h_tilde = tanh([wc,input] @ W_out). grid (B,2).
// ---------------------------------------------------------------------------
__global__ __launch_bounds__(256) void out_kernel(
    const float* __restrict__ wcp, const float* __restrict__ input,
    const float* __restrict__ W_out, float* __restrict__ out) {
  __shared__ float cat[2 * NH];
  const int b = blockIdx.x, half = blockIdx.y, t = threadIdx.x;
  for (int i = t; i < NH; i += 256) {
    float s = 0.f;
#pragma unroll
    for (int c = 0; c < 16; ++c) s += wcp[(size_t)(b * 16 + c) * NH + i];
    cat[i] = s;
    cat[NH + i] = input[b * NH + i];
  }
  __syncthreads();
  const int o = half * 256 + t;
  float acc = 0.f;
  for (int k = 0; k < 2 * NH; ++k) acc = fmaf(cat[k], W_out[(size_t)k * NH + o], acc);
  out[b * NH + o] = tanhf(acc);
}

// ---------------------------------------------------------------------------
extern "C" void kernel_launch(void* const* d_in, const int* in_sizes, int n_in,
                              void* d_out, int out_size, void* d_ws, size_t ws_size,
                              hipStream_t stream) {
  const float* input   = (const float*)d_in[0];
  const float* context = (const float*)d_in[1];
  const float* input_z = (const float*)d_in[2];
  const float* W_enc   = (const float*)d_in[3];
  const float* b_enc   = (const float*)d_in[4];
  const float* W_a     = (const float*)d_in[5];
  const float* b_a     = (const float*)d_in[6];
  const float* W_b     = (const float*)d_in[7];
  const float* b_b     = (const float*)d_in[8];
  const float* b_z     = (const float*)d_in[10];
  const float* W_z     = (const float*)d_in[9];
  const float* W_out   = (const float*)d_in[11];

  float* out = (float*)d_out;          // [0,32768): h_tilde, then gamma
  float* ws  = (float*)d_ws;           // all offsets keep 16B alignment
  float* pa  = ws;                     // 32768
  float* pb  = ws + 32768;             // 32768
  float* sa  = ws + 65536;             // 131072
  float* sb  = ws + 196608;            // 131072
  float* wcp = ws + 327680;            // 64*16*512 = 524288
  unsigned short* WhiE = (unsigned short*)(ws + 851968);   // 512*512 ush = 131072 f
  unsigned short* WloE = (unsigned short*)(ws + 983040);   // 131072 f
  unsigned short* WhiZ = (unsigned short*)(ws + 1114112);  // 128*512 ush = 32768 f
  unsigned short* WloZ = (unsigned short*)(ws + 1146880);  // 32768 f
  float* gamma = out + NB * NH;

  hipLaunchKernelGGL(pack_w_kernel, dim3(NH * NH / 256), dim3(256), 0, stream,
                     W_enc, WhiE, WloE);
  hipLaunchKernelGGL(pack_w_kernel, dim3(NF * NH / 256), dim3(256), 0, stream,
                     W_z, WhiZ, WloZ);
  hipLaunchKernelGGL(proj_in_kernel, dim3(NB, 4), dim3(256), 0, stream,
                     input, W_a, b_a, W_b, b_b, pa, pb);
  hipLaunchKernelGGL(score_mfma<NH>, dim3(NB * NS / 32), dim3(256), 0, stream,
                     context, WhiE, WloE, b_enc, pa, sa);
  hipLaunchKernelGGL(score_mfma<NF>, dim3(NB * NS / 32), dim3(256), 0, stream,
                     input_z, WhiZ, WloZ, b_z, pb, sb);
  hipLaunchKernelGGL(gamma_kernel, dim3(NB), dim3(256), 0, stream, sa, sb, gamma);
  hipLaunchKernelGGL(wctx_kernel, dim3(NB, 8), dim3(256), 0, stream,
                     context, gamma, wcp);
  hipLaunchKernelGGL(out_kernel, dim3(NB, 2), dim3(256), 0, stream,
                     wcp, input, W_out, out);
}

// Round 3
// 760.922 us; speedup vs baseline: 2.4323x; 1.1644x over previous
//
#include <hip/hip_runtime.h>
#include <math.h>

// DualAttention: B=64, S=2048, H=512, F=128, fp32 in/out.
#define NB 64
#define NS 2048
#define NH 512
#define NF 128

typedef __attribute__((ext_vector_type(8))) short bf16x8;   // 8 bf16 = 4 VGPRs
typedef __attribute__((ext_vector_type(4))) float f32x4;    // MFMA C/D

__device__ inline unsigned short f2bf(float x) {            // fp32->bf16 RNE
  union { float f; unsigned u; } v; v.f = x;
  unsigned r = v.u + 0x7fff + ((v.u >> 16) & 1);
  return (unsigned short)(r >> 16);
}
__device__ inline float bf2f(unsigned short b) {
  union { float f; unsigned u; } v; v.u = ((unsigned)b) << 16; return v.f;
}
__device__ inline float fast_tanh(float x) {
  float e = __expf(2.f * x);
  return 1.f - 2.f / (e + 1.f);
}
__device__ inline void split4(float4 p, ushort4& hv, ushort4& lv) {
  hv = make_ushort4(f2bf(p.x), f2bf(p.y), f2bf(p.z), f2bf(p.w));
  lv = make_ushort4(f2bf(p.x - bf2f(hv.x)), f2bf(p.y - bf2f(hv.y)),
                    f2bf(p.z - bf2f(hv.z)), f2bf(p.w - bf2f(hv.w)));
}

// ---------------------------------------------------------------------------
// Pack W [K,512] fp32 -> MFMA B-frag layout, split hi/lo bf16.
// linear = ((kt*32 + nt)*64 + lane)*8 + j ; k = kt*32+(lane>>4)*8+j, n = nt*16+(lane&15)
// ---------------------------------------------------------------------------
__global__ __launch_bounds__(256) void pack_w_kernel(
    const float* __restrict__ W, unsigned short* __restrict__ hi,
    unsigned short* __restrict__ lo) {
  const int tid = blockIdx.x * 256 + threadIdx.x;
  const int j = tid & 7, l = (tid >> 3) & 63, nt = (tid >> 9) & 31, kt = tid >> 14;
  const int k = kt * 32 + (l >> 4) * 8 + j;
  const int n = nt * 16 + (l & 15);
  const float x = W[k * NH + n];
  const unsigned short h = f2bf(x);
  hi[tid] = h;
  lo[tid] = f2bf(x - bf2f(h));
}

// ---------------------------------------------------------------------------
// Fused score GEMM, split-bf16 MFMA (3 products ~ fp32 precision):
//   score[r] = sum_n tanh((A[r,:] @ W[:,n]) + bias[n]) * pin[b,n]
// M=64 rows/block (halves per-block W L2 traffic vs M=32 — that was the R2
// bottleneck: 68 B/cyc/CU needed > ~56 B/cyc/CU L2 ceiling). 4 waves, wave w
// owns cols [w*128,(w+1)*128). A double-buffered in LDS as split bf16
// (row stride 40 ush = 80 B -> 16B-aligned b128); 1 barrier per K-step.
// ---------------------------------------------------------------------------
template <int K>
__global__ __launch_bounds__(256, 2) void score_mfma(
    const float* __restrict__ A,
    const unsigned short* __restrict__ Whi, const unsigned short* __restrict__ Wlo,
    const float* __restrict__ bias, const float* __restrict__ pin,
    float* __restrict__ score) {
  constexpr int KT = K / 32;
  __shared__ __align__(16) unsigned short lAhi[2][64 * 40];
  __shared__ __align__(16) unsigned short lAlo[2][64 * 40];
  __shared__ float red[4 * 64];
  const int t = threadIdx.x;
  const int wave = t >> 6, lane = t & 63;
  const int row0 = blockIdx.x * 64;
  const int b = row0 >> 11;  // row0 / S

  f32x4 acc[4][8];
#pragma unroll
  for (int mt = 0; mt < 4; ++mt)
#pragma unroll
    for (int nt = 0; nt < 8; ++nt) acc[mt][nt] = (f32x4)0.f;

  // staging: thread t loads float4 at rows {lr, lr+32}, col lc
  const int lr = t >> 3, lc = (t & 7) * 4;
  const float* Ab0 = A + (size_t)(row0 + lr) * K + lc;
  const float* Ab1 = Ab0 + (size_t)32 * K;
  const int fr = lane & 15, fq = lane >> 4;

  {  // prologue: stage kt=0 into buffer 0
    ushort4 hv, lv;
    const float4 p0 = *(const float4*)Ab0;
    const float4 p1 = *(const float4*)Ab1;
    split4(p0, hv, lv);
    *(ushort4*)&lAhi[0][lr * 40 + lc] = hv;
    *(ushort4*)&lAlo[0][lr * 40 + lc] = lv;
    split4(p1, hv, lv);
    *(ushort4*)&lAhi[0][(lr + 32) * 40 + lc] = hv;
    *(ushort4*)&lAlo[0][(lr + 32) * 40 + lc] = lv;
  }
  __syncthreads();

  for (int kt = 0; kt < KT; ++kt) {
    const int cur = kt & 1;
    // prefetch next A tile first — has the whole MFMA block to land
    float4 q0, q1;
    if (kt < KT - 1) {
      q0 = *(const float4*)(Ab0 + (kt + 1) * 32);
      q1 = *(const float4*)(Ab1 + (kt + 1) * 32);
    }
    bf16x8 ah[4], al[4];
#pragma unroll
    for (int mt = 0; mt < 4; ++mt) {
      const int ra = (mt * 16 + fr) * 40 + fq * 8;
      ah[mt] = *(const bf16x8*)&lAhi[cur][ra];
      al[mt] = *(const bf16x8*)&lAlo[cur][ra];
    }
#pragma unroll
    for (int nt = 0; nt < 8; ++nt) {
      const size_t widx = (size_t)(kt * 32 + wave * 8 + nt) * 64 + lane;  // bf16x8 units
      const bf16x8 wh = ((const bf16x8*)Whi)[widx];
      const bf16x8 wl = ((const bf16x8*)Wlo)[widx];
#pragma unroll
      for (int mt = 0; mt < 4; ++mt) {
        acc[mt][nt] = __builtin_amdgcn_mfma_f32_16x16x32_bf16(ah[mt], wh, acc[mt][nt], 0, 0, 0);
        acc[mt][nt] = __builtin_amdgcn_mfma_f32_16x16x32_bf16(ah[mt], wl, acc[mt][nt], 0, 0, 0);
        acc[mt][nt] = __builtin_amdgcn_mfma_f32_16x16x32_bf16(al[mt], wh, acc[mt][nt], 0, 0, 0);
      }
    }
    if (kt < KT - 1) {  // stage next tile into other buffer
      const int nxt = cur ^ 1;
      ushort4 hv, lv;
      split4(q0, hv, lv);
      *(ushort4*)&lAhi[nxt][lr * 40 + lc] = hv;
      *(ushort4*)&lAlo[nxt][lr * 40 + lc] = lv;
      split4(q1, hv, lv);
      *(ushort4*)&lAhi[nxt][(lr + 32) * 40 + lc] = hv;
      *(ushort4*)&lAlo[nxt][(lr + 32) * 40 + lc] = lv;
    }
    __syncthreads();
  }

  // Epilogue: tanh + weighted column-reduce.
  // C layout: col = nt*16 + (lane&15) + wave*128 ; row = mt*16 + (lane>>4)*4 + r.
  float ps[4][4];
#pragma unroll
  for (int mt = 0; mt < 4; ++mt)
#pragma unroll
    for (int r = 0; r < 4; ++r) ps[mt][r] = 0.f;
#pragma unroll
  for (int nt = 0; nt < 8; ++nt) {
    const int col = wave * 128 + nt * 16 + fr;
    const float bi = bias[col], pi = pin[b * NH + col];
#pragma unroll
    for (int mt = 0; mt < 4; ++mt)
#pragma unroll
      for (int r = 0; r < 4; ++r)
        ps[mt][r] += fast_tanh(acc[mt][nt][r] + bi) * pi;
  }
#pragma unroll
  for (int m = 8; m; m >>= 1)
#pragma unroll
    for (int mt = 0; mt < 4; ++mt)
#pragma unroll
      for (int r = 0; r < 4; ++r) ps[mt][r] += __shfl_xor(ps[mt][r], m);
  if (fr == 0)
#pragma unroll
    for (int mt = 0; mt < 4; ++mt)
#pragma unroll
      for (int r = 0; r < 4; ++r) red[wave * 64 + mt * 16 + fq * 4 + r] = ps[mt][r];
  __syncthreads();
  if (t < 64) score[row0 + t] = red[t] + red[64 + t] + red[128 + t] + red[192 + t];
}

// ---------------------------------------------------------------------------
// proj_in: tanh(input @ W_{a,b} + b_{a,b}); grid (B,4).
// ---------------------------------------------------------------------------
__global__ __launch_bounds__(256) void proj_in_kernel(
    const float* __restrict__ input,
    const float* __restrict__ W_a, const float* __restrict__ b_a,
    const float* __restrict__ W_b, const float* __restrict__ b_b,
    float* __restrict__ pa, float* __restrict__ pb) {
  __shared__ float sin_[NH];
  const int b = blockIdx.x, part = blockIdx.y, t = threadIdx.x;
  const float* W  = (part < 2) ? W_a : W_b;
  const float* bi = (part < 2) ? b_a : b_b;
  float* out      = (part < 2) ? pa : pb;
  const int h = t + (part & 1) * 256;
  sin_[t] = input[b * NH + t];
  sin_[t + 256] = input[b * NH + t + 256];
  __syncthreads();
  float acc = 0.f;
  for (int k = 0; k < NH; ++k) acc = fmaf(sin_[k], W[k * NH + h], acc);
  out[b * NH + h] = tanhf(acc + bi[h]);
}

// ---------------------------------------------------------------------------
// gamma = softmax_S(score_a + score_b)
// ---------------------------------------------------------------------------
__global__ __launch_bounds__(256) void gamma_kernel(
    const float* __restrict__ sa, const float* __restrict__ sb,
    float* __restrict__ gamma) {
  const int b = blockIdx.x, t = threadIdx.x;
  __shared__ float swp[4];
  float v[8];
  float mx = -1e30f;
#pragma unroll
  for (int i = 0; i < 8; ++i) {
    const int s = t + i * 256;
    v[i] = sa[b * NS + s] + sb[b * NS + s];
    mx = fmaxf(mx, v[i]);
  }
  const int wave = t >> 6, lane = t & 63;
#pragma unroll
  for (int off = 32; off; off >>= 1) mx = fmaxf(mx, __shfl_down(mx, off));
  if (lane == 0) swp[wave] = mx;
  __syncthreads();
  mx = fmaxf(fmaxf(swp[0], swp[1]), fmaxf(swp[2], swp[3]));
  __syncthreads();
  float sum = 0.f;
#pragma unroll
  for (int i = 0; i < 8; ++i) {
    v[i] = __expf(v[i] - mx);
    sum += v[i];
  }
#pragma unroll
  for (int off = 32; off; off >>= 1) sum += __shfl_down(sum, off);
  if (lane == 0) swp[wave] = sum;
  __syncthreads();
  const float inv = 1.f / (swp[0] + swp[1] + swp[2] + swp[3]);
#pragma unroll
  for (int i = 0; i < 8; ++i) gamma[b * NS + t + i * 256] = v[i] * inv;
}

// ---------------------------------------------------------------------------
// wctx partials: grid (B,8); float4 columns; wcp has 16 chunks per batch.
// ---------------------------------------------------------------------------
__global__ __launch_bounds__(256) void wctx_kernel(
    const float* __restrict__ ctx, const float* __restrict__ gamma,
    float* __restrict__ wcp) {
  const int b = blockIdx.x, ch = blockIdx.y, t = threadIdx.x;
  __shared__ float g[256];
  const int s0 = ch * 256;
  g[t] = gamma[b * NS + s0 + t];
  __syncthreads();
  const int sh = t >> 7, h4 = (t & 127) * 4;
  float4 acc = make_float4(0.f, 0.f, 0.f, 0.f);
  const float* base = ctx + (size_t)(b * NS + s0 + sh * 128) * NH + h4;
#pragma unroll 4
  for (int s = 0; s < 128; ++s) {
    const float gs = g[sh * 128 + s];
    const float4 c = *(const float4*)(base + (size_t)s * NH);
    acc.x = fmaf(gs, c.x, acc.x);
    acc.y = fmaf(gs, c.y, acc.y);
    acc.z = fmaf(gs, c.z, acc.z);
    acc.w = fmaf(gs, c.w, acc.w);
  }
  *(float4*)&wcp[(size_t)(b * 16 + ch * 2 + sh) * NH + h4] = acc;
}

// ---------------------------------------------------------------------------
// out: reduce 16 wcp chunks -> wc; h_tilde = tanh([wc,input] @ W_out). grid (B,2).
// ---------------------------------------------------------------------------
__global__ __launch_bounds__(256) void out_kernel(
    const float* __restrict__ wcp, const float* __restrict__ input,
    const float* __restrict__ W_out, float* __restrict__ out) {
  __shared__ float cat[2 * NH];
  const int b = blockIdx.x, half = blockIdx.y, t = threadIdx.x;
  for (int i = t; i < NH; i += 256) {
    float s = 0.f;
#pragma unroll
    for (int c = 0; c < 16; ++c) s += wcp[(size_t)(b * 16 + c) * NH + i];
    cat[i] = s;
    cat[NH + i] = input[b * NH + i];
  }
  __syncthreads();
  const int o = half * 256 + t;
  float acc = 0.f;
  for (int k = 0; k < 2 * NH; ++k) acc = fmaf(cat[k], W_out[(size_t)k * NH + o], acc);
  out[b * NH + o] = tanhf(acc);
}

// ---------------------------------------------------------------------------
extern "C" void kernel_launch(void* const* d_in, const int* in_sizes, int n_in,
                              void* d_out, int out_size, void* d_ws, size_t ws_size,
                              hipStream_t stream) {
  const float* input   = (const float*)d_in[0];
  const float* context = (const float*)d_in[1];
  const float* input_z = (const float*)d_in[2];
  const float* W_enc   = (const float*)d_in[3];
  const float* b_enc   = (const float*)d_in[4];
  const float* W_a     = (const float*)d_in[5];
  const float* b_a     = (const float*)d_in[6];
  const float* W_b     = (const float*)d_in[7];
  const float* b_b     = (const float*)d_in[8];
  const float* W_z     = (const float*)d_in[9];
  const float* b_z     = (const float*)d_in[10];
  const float* W_out   = (const float*)d_in[11];

  float* out = (float*)d_out;          // [0,32768): h_tilde, then gamma
  float* ws  = (float*)d_ws;
  float* pa  = ws;                     // 32768
  float* pb  = ws + 32768;             // 32768
  float* sa  = ws + 65536;             // 131072
  float* sb  = ws + 196608;            // 131072
  float* wcp = ws + 327680;            // 64*16*512 = 524288
  unsigned short* WhiE = (unsigned short*)(ws + 851968);   // 512*512 ush
  unsigned short* WloE = (unsigned short*)(ws + 983040);
  unsigned short* WhiZ = (unsigned short*)(ws + 1114112);  // 128*512 ush
  unsigned short* WloZ = (unsigned short*)(ws + 1146880);
  float* gamma = out + NB * NH;

  hipLaunchKernelGGL(pack_w_kernel, dim3(NH * NH / 256), dim3(256), 0, stream,
                     W_enc, WhiE, WloE);
  hipLaunchKernelGGL(pack_w_kernel, dim3(NF * NH / 256), dim3(256), 0, stream,
                     W_z, WhiZ, WloZ);
  hipLaunchKernelGGL(proj_in_kernel, dim3(NB, 4), dim3(256), 0, stream,
                     input, W_a, b_a, W_b, b_b, pa, pb);
  hipLaunchKernelGGL(score_mfma<NH>, dim3(NB * NS / 64), dim3(256), 0, stream,
                     context, WhiE, WloE, b_enc, pa, sa);
  hipLaunchKernelGGL(score_mfma<NF>, dim3(NB * NS / 64), dim3(256), 0, stream,
                     input_z, WhiZ, WloZ, b_z, pb, sb);
  hipLaunchKernelGGL(gamma_kernel, dim3(NB), dim3(256), 0, stream, sa, sb, gamma);
  hipLaunchKernelGGL(wctx_kernel, dim3(NB, 8), dim3(256), 0, stream,
                     context, gamma, wcp);
  hipLaunchKernelGGL(out_kernel, dim3(NB, 2), dim3(256), 0, stream,
                     wcp, input, W_out, out);
}